// Round 7
// baseline (40479.651 us; speedup 1.0000x reference)
//
#include <hip/hip_runtime.h>
#include <hip/hip_cooperative_groups.h>
#include <math.h>

namespace cg = cooperative_groups;

#define BB 64
#define SS 512
#define INF 64
#define HH 512
#define G5 2560

// ---------------- init: zero recurrent state ----------------
__global__ void init_kernel(float* __restrict__ p, int n) {
    int i = blockIdx.x * blockDim.x + threadIdx.x;
    if (i < n) p[i] = 0.f;
}

// ---------------- weight repack ----------------
// P[(g*10 + gate*2 + c)*K + k] = W[k*G5 + gate*512 + g*2 + c]   (j = g*2+c)
__global__ __launch_bounds__(256) void repack_kernel(
    const float* __restrict__ W, float* __restrict__ P, int K)
{
    __shared__ float tile[64][65];
    const int tid = threadIdx.x;
    const int kt = blockIdx.x;
    const int c0 = blockIdx.y * 64;      // 64 cols, never spans a gate

    for (int e = tid; e < 64 * 16; e += 256) {
        int kr = e >> 4, cq = (e & 15) * 4;
        float4 v = *(const float4*)(W + (size_t)(kt * 64 + kr) * G5 + c0 + cq);
        tile[kr][cq + 0] = v.x; tile[kr][cq + 1] = v.y;
        tile[kr][cq + 2] = v.z; tile[kr][cq + 3] = v.w;
    }
    __syncthreads();

    const int gate = c0 >> 9;
    const int jb   = c0 & 511;           // base j within gate (even)
    for (int e = tid; e < 64 * 16; e += 256) {
        int lr = e >> 4;                 // local col 0..63
        int kq = (e & 15) * 4;
        int j  = jb + lr;
        int g  = j >> 1;
        int c  = j & 1;
        int orow = g * 10 + gate * 2 + c;
        float4 v;
        v.x = tile[kq + 0][lr]; v.y = tile[kq + 1][lr];
        v.z = tile[kq + 2][lr]; v.w = tile[kq + 3][lr];
        *(float4*)(P + (size_t)orow * K + kt * 64 + kq) = v;
    }
}

// ---------------- x transpose to quad-interleaved: xT[t][k>>2][row][k&3] ----
__global__ __launch_bounds__(256) void xpose_kernel(
    const float* __restrict__ x, float* __restrict__ xT)
{
    __shared__ float tile[64][68];
    const int tid = threadIdx.x;
    const int t = blockIdx.x;

    for (int e = tid; e < 64 * 16; e += 256) {
        int row = e >> 4, kq = (e & 15) * 4;
        float4 v = *(const float4*)(x + ((size_t)row * SS + t) * INF + kq);
        tile[row][kq + 0] = v.x; tile[row][kq + 1] = v.y;
        tile[row][kq + 2] = v.z; tile[row][kq + 3] = v.w;
    }
    __syncthreads();
    float* dst = xT + (size_t)t * (INF * BB);
    for (int e = tid; e < INF * BB; e += 256) {
        int k = e >> 6, r = e & 63;
        dst[(k >> 2) * 256 + r * 4 + (k & 3)] = tile[r][k];
    }
}

// ======================= core step body (shared logic) =======================
// Layouts: h buffers quad-interleaved [k>>2][row][4] (32768 floats per state).
// Block owns 2 output cols j = g*2 + {0,1}; 4 waves split K in quarters.
// W slice resident in W_s (10 rows x K). red[] for cross-wave K reduction.

// ---------------- persistent cooperative kernel ----------------
__global__ __launch_bounds__(256, 2) void persist_kernel(
    const float* __restrict__ xT,
    const float* __restrict__ P0, const float* __restrict__ b0v,
    const float* __restrict__ P1, const float* __restrict__ b1v,
    float* __restrict__ h0buf, float* __restrict__ h1buf,
    float* __restrict__ lstm_out)
{
    __shared__ float W_s[10 * 1024];          // 40 KB
    __shared__ float red[4][10][64];          // 10 KB

    cg::grid_group grid = cg::this_grid();

    const int tid  = threadIdx.x;
    const int lane = tid & 63;          // batch row
    const int wv   = tid >> 6;          // K-quarter; waves 0/1 also own col wv
    const bool isL1 = (blockIdx.x >= 256);
    const int blk  = (int)blockIdx.x & 255;
    const int g    = (blk & 7) * 32 + (blk >> 3);   // XCD-pinned col pair
    const int j    = g * 2 + (wv & 1);  // valid for wv<2 epilogue

    const int K  = isL1 ? 1024 : 576;
    const int QK = K >> 2;              // 256 or 144
    const int NQ = QK >> 2;             // 64 or 36 (even)
    const int k0 = wv * QK;

    // ---- one-time: W slice -> LDS ----
    {
        const float* Pg = (isL1 ? P1 : P0) + (size_t)g * 10 * K;
        const int n4 = 10 * K / 4;
        for (int i = tid; i < n4; i += 256)
            *(float4*)&W_s[i * 4] = *(const float4*)(Pg + (size_t)i * 4);
    }
    float bias[5];
    if (wv < 2) {
        const float* bv = isL1 ? b1v : b0v;
        #pragma unroll
        for (int gate = 0; gate < 5; ++gate) bias[gate] = bv[gate * HH + j];
    }
    float c_reg = 0.f;
    __syncthreads();

    const float4* wP = (const float4*)W_s + (k0 >> 2);
    const int K4 = K >> 2;

    for (int t = 0; t <= SS; ++t) {
        const bool active = isL1 ? (t >= 1) : (t < SS);
        if (active) {
            const int tm1 = t - 1;
            const float* h0prev = h0buf + ((t + 1) & 1) * (BB * HH);
            const float* h0cur  = h0buf + (tm1 & 1) * (BB * HH);
            const float* h1prev = h1buf + ((tm1 + 1) & 1) * (BB * HH);

            // per-wave A base pointers (float4 units; quad q -> [q*64])
            const float4* aP0;
            const float4* aP1;
            int bnd;
            if (!isL1) {
                if (wv == 0) {
                    aP0 = (const float4*)(xT + (size_t)t * (INF * BB)) + lane;
                    aP1 = (const float4*)h0prev + lane;
                    bnd = 16;
                } else {
                    aP0 = (const float4*)h0prev + (36 * wv - 16) * 64 + lane;
                    aP1 = aP0;
                    bnd = NQ;
                }
            } else {
                const float* src = (wv < 2) ? h0cur : h1prev;
                aP0 = (const float4*)src + (wv & 1) * 4096 + lane;
                aP1 = aP0;
                bnd = NQ;
            }

            float acc[10];
            #pragma unroll
            for (int r = 0; r < 10; ++r) acc[r] = 0.f;

            float4 wA[10], wB[10];
            float4 a0, a1, a2, a3;

            a0 = aP0[0];
            a1 = (1 < bnd) ? aP0[64] : aP1[(1 - bnd) * 64];
            #pragma unroll
            for (int r = 0; r < 10; ++r) wA[r] = wP[r * K4];

            for (int q = 0; q < NQ; q += 2) {
                {
                    const float4* p1 = (const float4*)W_s + (k0 >> 2) + (q + 1);
                    #pragma unroll
                    for (int r = 0; r < 10; ++r) wB[r] = p1[r * K4];
                }
                if (q + 2 < NQ) {
                    const float4* p = (q + 2 < bnd) ? (aP0 + (q + 2) * 64)
                                                    : (aP1 + (q + 2 - bnd) * 64);
                    a2 = *p;
                } else a2 = a0;
                #pragma unroll
                for (int r = 0; r < 10; ++r) {
                    acc[r] = fmaf(a0.x, wA[r].x, acc[r]);
                    acc[r] = fmaf(a0.y, wA[r].y, acc[r]);
                    acc[r] = fmaf(a0.z, wA[r].z, acc[r]);
                    acc[r] = fmaf(a0.w, wA[r].w, acc[r]);
                }
                if (q + 2 < NQ) {
                    const float4* p2 = (const float4*)W_s + (k0 >> 2) + (q + 2);
                    #pragma unroll
                    for (int r = 0; r < 10; ++r) wA[r] = p2[r * K4];
                }
                if (q + 3 < NQ) {
                    const float4* p = (q + 3 < bnd) ? (aP0 + (q + 3) * 64)
                                                    : (aP1 + (q + 3 - bnd) * 64);
                    a3 = *p;
                } else a3 = a1;
                #pragma unroll
                for (int r = 0; r < 10; ++r) {
                    acc[r] = fmaf(a1.x, wB[r].x, acc[r]);
                    acc[r] = fmaf(a1.y, wB[r].y, acc[r]);
                    acc[r] = fmaf(a1.z, wB[r].z, acc[r]);
                    acc[r] = fmaf(a1.w, wB[r].w, acc[r]);
                }
                a0 = a2; a1 = a3;
            }

            #pragma unroll
            for (int r = 0; r < 10; ++r) red[wv][r][lane] = acc[r];
            __syncthreads();

            if (wv < 2) {
                float gv[5];
                #pragma unroll
                for (int gate = 0; gate < 5; ++gate) {
                    int r = gate * 2 + wv;
                    gv[gate] = red[0][r][lane] + red[1][r][lane]
                             + red[2][r][lane] + red[3][r][lane] + bias[gate];
                }
                float f  = 1.f / (1.f + expf(-gv[0]));
                float i_ = 1.f / (1.f + expf(-gv[1]));
                float ch = tanhf(gv[2]);
                float o  = 1.f / (1.f + expf(-gv[3]));
                float e_ = 1.f / (1.f + expf(-gv[4]));

                c_reg = f * c_reg + i_ * ch;
                float hl = o * tanhf(c_reg);
                float hn = e_ * expf(hl) + (1.f - e_) * hl;

                const int hoff = (j >> 2) * 256 + lane * 4 + (j & 3);
                if (!isL1) {
                    h0buf[(t & 1) * (BB * HH) + hoff] = hn;
                } else {
                    h1buf[(tm1 & 1) * (BB * HH) + hoff] = hn;
                    lstm_out[((size_t)lane * SS + tm1) * HH + j] = hn;
                }
            }
        }
        grid.sync();
    }
}

// ---------------- fallback per-step kernel (same geometry, global c) --------
__global__ __launch_bounds__(256, 2) void step512_kernel(
    const float* __restrict__ xT,
    const float* __restrict__ P0, const float* __restrict__ b0v,
    const float* __restrict__ P1, const float* __restrict__ b1v,
    float* __restrict__ h0buf, float* __restrict__ h1buf,
    float* __restrict__ c0buf, float* __restrict__ c1buf,
    float* __restrict__ lstm_out, int t)
{
    __shared__ float W_s[10 * 1024];
    __shared__ float red[4][10][64];

    const int tid  = threadIdx.x;
    const int lane = tid & 63;
    const int wv   = tid >> 6;
    const bool isL1 = (blockIdx.x >= 256);
    const int blk  = (int)blockIdx.x & 255;
    const int g    = (blk & 7) * 32 + (blk >> 3);
    const int j    = g * 2 + (wv & 1);

    const bool active = isL1 ? (t >= 1) : (t < SS);
    if (!active) return;

    const int K  = isL1 ? 1024 : 576;
    const int QK = K >> 2;
    const int NQ = QK >> 2;
    const int k0 = wv * QK;

    {
        const float* Pg = (isL1 ? P1 : P0) + (size_t)g * 10 * K;
        const int n4 = 10 * K / 4;
        for (int i = tid; i < n4; i += 256)
            *(float4*)&W_s[i * 4] = *(const float4*)(Pg + (size_t)i * 4);
    }
    __syncthreads();

    const int tm1 = t - 1;
    const float* h0prev = h0buf + ((t + 1) & 1) * (BB * HH);
    const float* h0cur  = h0buf + (tm1 & 1) * (BB * HH);
    const float* h1prev = h1buf + ((tm1 + 1) & 1) * (BB * HH);

    const float4* aP0;
    const float4* aP1;
    int bnd;
    if (!isL1) {
        if (wv == 0) {
            aP0 = (const float4*)(xT + (size_t)t * (INF * BB)) + lane;
            aP1 = (const float4*)h0prev + lane;
            bnd = 16;
        } else {
            aP0 = (const float4*)h0prev + (36 * wv - 16) * 64 + lane;
            aP1 = aP0;
            bnd = NQ;
        }
    } else {
        const float* src = (wv < 2) ? h0cur : h1prev;
        aP0 = (const float4*)src + (wv & 1) * 4096 + lane;
        aP1 = aP0;
        bnd = NQ;
    }

    const float4* wP = (const float4*)W_s + (k0 >> 2);
    const int K4 = K >> 2;

    float acc[10];
    #pragma unroll
    for (int r = 0; r < 10; ++r) acc[r] = 0.f;

    float4 wA[10], wB[10];
    float4 a0, a1, a2, a3;
    a0 = aP0[0];
    a1 = (1 < bnd) ? aP0[64] : aP1[(1 - bnd) * 64];
    #pragma unroll
    for (int r = 0; r < 10; ++r) wA[r] = wP[r * K4];

    for (int q = 0; q < NQ; q += 2) {
        {
            const float4* p1 = (const float4*)W_s + (k0 >> 2) + (q + 1);
            #pragma unroll
            for (int r = 0; r < 10; ++r) wB[r] = p1[r * K4];
        }
        if (q + 2 < NQ) {
            const float4* p = (q + 2 < bnd) ? (aP0 + (q + 2) * 64)
                                            : (aP1 + (q + 2 - bnd) * 64);
            a2 = *p;
        } else a2 = a0;
        #pragma unroll
        for (int r = 0; r < 10; ++r) {
            acc[r] = fmaf(a0.x, wA[r].x, acc[r]);
            acc[r] = fmaf(a0.y, wA[r].y, acc[r]);
            acc[r] = fmaf(a0.z, wA[r].z, acc[r]);
            acc[r] = fmaf(a0.w, wA[r].w, acc[r]);
        }
        if (q + 2 < NQ) {
            const float4* p2 = (const float4*)W_s + (k0 >> 2) + (q + 2);
            #pragma unroll
            for (int r = 0; r < 10; ++r) wA[r] = p2[r * K4];
        }
        if (q + 3 < NQ) {
            const float4* p = (q + 3 < bnd) ? (aP0 + (q + 3) * 64)
                                            : (aP1 + (q + 3 - bnd) * 64);
            a3 = *p;
        } else a3 = a1;
        #pragma unroll
        for (int r = 0; r < 10; ++r) {
            acc[r] = fmaf(a1.x, wB[r].x, acc[r]);
            acc[r] = fmaf(a1.y, wB[r].y, acc[r]);
            acc[r] = fmaf(a1.z, wB[r].z, acc[r]);
            acc[r] = fmaf(a1.w, wB[r].w, acc[r]);
        }
        a0 = a2; a1 = a3;
    }

    #pragma unroll
    for (int r = 0; r < 10; ++r) red[wv][r][lane] = acc[r];
    __syncthreads();

    if (wv < 2) {
        const float* bv = isL1 ? b1v : b0v;
        float gv[5];
        #pragma unroll
        for (int gate = 0; gate < 5; ++gate) {
            int r = gate * 2 + wv;
            gv[gate] = red[0][r][lane] + red[1][r][lane]
                     + red[2][r][lane] + red[3][r][lane] + bv[gate * HH + j];
        }
        float f  = 1.f / (1.f + expf(-gv[0]));
        float i_ = 1.f / (1.f + expf(-gv[1]));
        float ch = tanhf(gv[2]);
        float o  = 1.f / (1.f + expf(-gv[3]));
        float e_ = 1.f / (1.f + expf(-gv[4]));

        float* cb = (isL1 ? c1buf : c0buf) + j * BB + lane;
        float c = f * (*cb) + i_ * ch;
        *cb = c;
        float hl = o * tanhf(c);
        float hn = e_ * expf(hl) + (1.f - e_) * hl;

        const int hoff = (j >> 2) * 256 + lane * 4 + (j & 3);
        if (!isL1) {
            h0buf[(t & 1) * (BB * HH) + hoff] = hn;
        } else {
            h1buf[(tm1 & 1) * (BB * HH) + hoff] = hn;
            lstm_out[((size_t)lane * SS + tm1) * HH + j] = hn;
        }
    }
}

// ---------------- attention epilogue, one block per batch row ----------------
__global__ __launch_bounds__(256) void attn_kernel(
    const float* __restrict__ lstm_out,
    const float* __restrict__ Wa, const float* __restrict__ ba,
    const float* __restrict__ Wfc, const float* __restrict__ bfc,
    float* __restrict__ dout)
{
    const int b = blockIdx.x;
    const int tid = threadIdx.x;
    const int lane = tid & 63;
    const int wave = tid >> 6;

    __shared__ float wa_s[HH];
    __shared__ float logit[SS];
    __shared__ float wred[4];

    for (int ii = tid; ii < HH; ii += 256) wa_s[ii] = Wa[ii];
    __syncthreads();

    const float* Lb = lstm_out + (size_t)b * SS * HH;

    for (int tt = wave; tt < SS; tt += 4) {
        const float* rowp = Lb + (size_t)tt * HH;
        float s = 0.f;
        for (int jc = lane; jc < HH; jc += 64) s += rowp[jc] * wa_s[jc];
        #pragma unroll
        for (int off = 32; off > 0; off >>= 1) s += __shfl_down(s, off, 64);
        if (lane == 0) logit[tt] = s + ba[0];
    }
    __syncthreads();

    float m = -1e30f;
    for (int ii = tid; ii < SS; ii += 256) m = fmaxf(m, logit[ii]);
    #pragma unroll
    for (int off = 32; off > 0; off >>= 1) m = fmaxf(m, __shfl_down(m, off, 64));
    if (lane == 0) wred[wave] = m;
    __syncthreads();
    m = fmaxf(fmaxf(wred[0], wred[1]), fmaxf(wred[2], wred[3]));
    __syncthreads();

    float ssum = 0.f;
    for (int ii = tid; ii < SS; ii += 256) {
        float e = expf(logit[ii] - m);
        logit[ii] = e;
        ssum += e;
    }
    #pragma unroll
    for (int off = 32; off > 0; off >>= 1) ssum += __shfl_down(ssum, off, 64);
    if (lane == 0) wred[wave] = ssum;
    __syncthreads();
    ssum = wred[0] + wred[1] + wred[2] + wred[3];
    float inv = 1.f / ssum;
    __syncthreads();

    for (int ii = tid; ii < SS; ii += 256) {
        float a = logit[ii] * inv;
        logit[ii] = a;
        dout[BB + (size_t)b * SS + ii] = a;
    }
    __syncthreads();

    float ctx0 = 0.f, ctx1 = 0.f;
    for (int tt = 0; tt < SS; ++tt) {
        float a = logit[tt];
        ctx0 += a * Lb[(size_t)tt * HH + tid];
        ctx1 += a * Lb[(size_t)tt * HH + tid + 256];
    }

    float p = ctx0 * Wfc[tid] + ctx1 * Wfc[tid + 256];
    #pragma unroll
    for (int off = 32; off > 0; off >>= 1) p += __shfl_down(p, off, 64);
    __syncthreads();
    if (lane == 0) wred[wave] = p;
    __syncthreads();
    if (tid == 0) dout[b] = wred[0] + wred[1] + wred[2] + wred[3] + bfc[0];
}

extern "C" void kernel_launch(void* const* d_in, const int* in_sizes, int n_in,
                              void* d_out, int out_size, void* d_ws, size_t ws_size,
                              hipStream_t stream) {
    const float* x   = (const float*)d_in[0];
    const float* W0  = (const float*)d_in[1];
    const float* b0  = (const float*)d_in[2];
    const float* W1  = (const float*)d_in[3];
    const float* b1  = (const float*)d_in[4];
    const float* Wa  = (const float*)d_in[5];
    const float* ba  = (const float*)d_in[6];
    const float* Wfc = (const float*)d_in[7];
    const float* bfc = (const float*)d_in[8];
    float* out = (float*)d_out;
    float* ws  = (float*)d_ws;

    float* h0   = ws;                              // 2*H*B (quad-interleaved)
    float* h1   = h0 + 2 * BB * HH;                // 2*H*B
    float* c0   = h1 + 2 * BB * HH;                // H*B (fallback only)
    float* c1   = c0 + BB * HH;                    // H*B (fallback only)
    float* lstm = c1 + BB * HH;                    // B*S*H
    float* P0   = lstm + (size_t)BB * SS * HH;     // 2560*576
    float* P1   = P0 + (size_t)G5 * (INF + HH);    // 2560*1024
    float* xT   = P1 + (size_t)G5 * (HH + HH);     // S*IN*B

    const int state_n = 6 * BB * HH;
    init_kernel<<<(state_n + 255) / 256, 256, 0, stream>>>(ws, state_n);

    repack_kernel<<<dim3((INF + HH) / 64, 40), 256, 0, stream>>>(W0, P0, INF + HH);
    repack_kernel<<<dim3((HH + HH) / 64, 40), 256, 0, stream>>>(W1, P1, HH + HH);
    xpose_kernel<<<SS, 256, 0, stream>>>(x, xT);

    void* args[] = { (void*)&xT, (void*)&P0, (void*)&b0, (void*)&P1, (void*)&b1,
                     (void*)&h0, (void*)&h1, (void*)&lstm };
    hipError_t cerr = hipLaunchCooperativeKernel((void*)persist_kernel,
                                                 dim3(512), dim3(256),
                                                 args, 0, stream);
    if (cerr != hipSuccess) {
        for (int t = 0; t <= SS; ++t) {
            step512_kernel<<<512, 256, 0, stream>>>(xT, P0, b0, P1, b1,
                                                    h0, h1, c0, c1, lstm, t);
        }
    }

    attn_kernel<<<BB, 256, 0, stream>>>(lstm, Wa, ba, Wfc, bfc, out);
}

// Round 8
// 20507.278 us; speedup vs baseline: 1.9739x; 1.9739x over previous
//
#include <hip/hip_runtime.h>
#include <hip/hip_cooperative_groups.h>
#include <math.h>

namespace cg = cooperative_groups;

#define BB 64
#define SS 512
#define INF 64
#define HH 512
#define G5 2560

// ---------------- init: zero recurrent state (+ barrier words) ----------------
__global__ void init_kernel(float* __restrict__ p, int n) {
    int i = blockIdx.x * blockDim.x + threadIdx.x;
    if (i < n) p[i] = 0.f;
}

// ---------------- weight repack ----------------
// P[(g*10 + gate*2 + c)*K + k] = W[k*G5 + gate*512 + g*2 + c]   (j = g*2+c)
__global__ __launch_bounds__(256) void repack_kernel(
    const float* __restrict__ W, float* __restrict__ P, int K)
{
    __shared__ float tile[64][65];
    const int tid = threadIdx.x;
    const int kt = blockIdx.x;
    const int c0 = blockIdx.y * 64;      // 64 cols, never spans a gate

    for (int e = tid; e < 64 * 16; e += 256) {
        int kr = e >> 4, cq = (e & 15) * 4;
        float4 v = *(const float4*)(W + (size_t)(kt * 64 + kr) * G5 + c0 + cq);
        tile[kr][cq + 0] = v.x; tile[kr][cq + 1] = v.y;
        tile[kr][cq + 2] = v.z; tile[kr][cq + 3] = v.w;
    }
    __syncthreads();

    const int gate = c0 >> 9;
    const int jb   = c0 & 511;
    for (int e = tid; e < 64 * 16; e += 256) {
        int lr = e >> 4;
        int kq = (e & 15) * 4;
        int j  = jb + lr;
        int g  = j >> 1;
        int c  = j & 1;
        int orow = g * 10 + gate * 2 + c;
        float4 v;
        v.x = tile[kq + 0][lr]; v.y = tile[kq + 1][lr];
        v.z = tile[kq + 2][lr]; v.w = tile[kq + 3][lr];
        *(float4*)(P + (size_t)orow * K + kt * 64 + kq) = v;
    }
}

// ---------------- x transpose to quad-interleaved: xT[t][k>>2][row][k&3] ----
__global__ __launch_bounds__(256) void xpose_kernel(
    const float* __restrict__ x, float* __restrict__ xT)
{
    __shared__ float tile[64][68];
    const int tid = threadIdx.x;
    const int t = blockIdx.x;

    for (int e = tid; e < 64 * 16; e += 256) {
        int row = e >> 4, kq = (e & 15) * 4;
        float4 v = *(const float4*)(x + ((size_t)row * SS + t) * INF + kq);
        tile[row][kq + 0] = v.x; tile[row][kq + 1] = v.y;
        tile[row][kq + 2] = v.z; tile[row][kq + 3] = v.w;
    }
    __syncthreads();
    float* dst = xT + (size_t)t * (INF * BB);
    for (int e = tid; e < INF * BB; e += 256) {
        int k = e >> 6, r = e & 63;
        dst[(k >> 2) * 256 + r * 4 + (k & 3)] = tile[r][k];
    }
}

// ---------------- custom two-level device barrier ----------------
// bar layout (uints): [g*16] 8 group counters (64B apart), [128] root, [144] phase.
// Cumulative counts (no reset). Leaders: release-add -> (group completer)
// release-add root -> (root completer) release-store phase = t+1.
// All leaders tight-spin relaxed-agent on phase, then one acquire load.
__device__ __forceinline__ void xbar(unsigned* bar, int t) {
    __syncthreads();                     // drains each wave's vmem (waitcnt before s_barrier)
    if (threadIdx.x == 0) {
        const unsigned want = (unsigned)(t + 1);
        unsigned* gc    = bar + ((blockIdx.x & 7) * 16);
        unsigned* root  = bar + 128;
        unsigned* phase = bar + 144;
        unsigned r = __hip_atomic_fetch_add(gc, 1u, __ATOMIC_RELEASE,
                                            __HIP_MEMORY_SCOPE_AGENT);
        if (r == want * 64u - 1u) {
            unsigned r2 = __hip_atomic_fetch_add(root, 1u, __ATOMIC_ACQ_REL,
                                                 __HIP_MEMORY_SCOPE_AGENT);
            if (r2 == want * 8u - 1u) {
                __hip_atomic_store(phase, want, __ATOMIC_RELEASE,
                                   __HIP_MEMORY_SCOPE_AGENT);
            }
        }
        while (__hip_atomic_load(phase, __ATOMIC_RELAXED,
                                 __HIP_MEMORY_SCOPE_AGENT) < want) {}
        (void)__hip_atomic_load(phase, __ATOMIC_ACQUIRE,
                                __HIP_MEMORY_SCOPE_AGENT);   // L1/L2 invalidate
    }
    __syncthreads();
}

// ---------------- persistent cooperative kernel ----------------
__global__ __launch_bounds__(256, 2) void persist_kernel(
    const float* __restrict__ xT,
    const float* __restrict__ P0, const float* __restrict__ b0v,
    const float* __restrict__ P1, const float* __restrict__ b1v,
    float* __restrict__ h0buf, float* __restrict__ h1buf,
    float* __restrict__ lstm_out, unsigned* __restrict__ bar)
{
    __shared__ float W_s[10 * 1024];          // 40 KB
    __shared__ float red[4][10][64];          // 10 KB

    const int tid  = threadIdx.x;
    const int lane = tid & 63;          // batch row
    const int wv   = tid >> 6;          // K-quarter; waves 0/1 also own col wv
    const bool isL1 = (blockIdx.x >= 256);
    const int blk  = (int)blockIdx.x & 255;
    const int g    = (blk & 7) * 32 + (blk >> 3);   // XCD-pinned col pair
    const int j    = g * 2 + (wv & 1);

    const int K  = isL1 ? 1024 : 576;
    const int QK = K >> 2;              // 256 or 144
    const int NQ = QK >> 2;             // 64 or 36 (even)
    const int k0 = wv * QK;

    // ---- one-time: W slice -> LDS ----
    {
        const float* Pg = (isL1 ? P1 : P0) + (size_t)g * 10 * K;
        const int n4 = 10 * K / 4;
        for (int i = tid; i < n4; i += 256)
            *(float4*)&W_s[i * 4] = *(const float4*)(Pg + (size_t)i * 4);
    }
    float bias[5];
    if (wv < 2) {
        const float* bv = isL1 ? b1v : b0v;
        #pragma unroll
        for (int gate = 0; gate < 5; ++gate) bias[gate] = bv[gate * HH + j];
    }
    float c_reg = 0.f;
    __syncthreads();

    const float4* wP = (const float4*)W_s + (k0 >> 2);
    const int K4 = K >> 2;

    for (int t = 0; t <= SS; ++t) {
        const bool active = isL1 ? (t >= 1) : (t < SS);
        if (active) {
            const int tm1 = t - 1;
            const float* h0prev = h0buf + ((t + 1) & 1) * (BB * HH);
            const float* h0cur  = h0buf + (tm1 & 1) * (BB * HH);
            const float* h1prev = h1buf + ((tm1 + 1) & 1) * (BB * HH);

            const float4* aP0;
            const float4* aP1;
            int bnd;
            if (!isL1) {
                if (wv == 0) {
                    aP0 = (const float4*)(xT + (size_t)t * (INF * BB)) + lane;
                    aP1 = (const float4*)h0prev + lane;
                    bnd = 16;
                } else {
                    aP0 = (const float4*)h0prev + (36 * wv - 16) * 64 + lane;
                    aP1 = aP0;
                    bnd = NQ;
                }
            } else {
                const float* src = (wv < 2) ? h0cur : h1prev;
                aP0 = (const float4*)src + (wv & 1) * 4096 + lane;
                aP1 = aP0;
                bnd = NQ;
            }

            float acc[10];
            #pragma unroll
            for (int r = 0; r < 10; ++r) acc[r] = 0.f;

            float4 wA[10], wB[10];
            float4 a0, a1, a2, a3;

            a0 = aP0[0];
            a1 = (1 < bnd) ? aP0[64] : aP1[(1 - bnd) * 64];
            #pragma unroll
            for (int r = 0; r < 10; ++r) wA[r] = wP[r * K4];

            for (int q = 0; q < NQ; q += 2) {
                {
                    const float4* p1 = (const float4*)W_s + (k0 >> 2) + (q + 1);
                    #pragma unroll
                    for (int r = 0; r < 10; ++r) wB[r] = p1[r * K4];
                }
                if (q + 2 < NQ) {
                    const float4* p = (q + 2 < bnd) ? (aP0 + (q + 2) * 64)
                                                    : (aP1 + (q + 2 - bnd) * 64);
                    a2 = *p;
                } else a2 = a0;
                #pragma unroll
                for (int r = 0; r < 10; ++r) {
                    acc[r] = fmaf(a0.x, wA[r].x, acc[r]);
                    acc[r] = fmaf(a0.y, wA[r].y, acc[r]);
                    acc[r] = fmaf(a0.z, wA[r].z, acc[r]);
                    acc[r] = fmaf(a0.w, wA[r].w, acc[r]);
                }
                if (q + 2 < NQ) {
                    const float4* p2 = (const float4*)W_s + (k0 >> 2) + (q + 2);
                    #pragma unroll
                    for (int r = 0; r < 10; ++r) wA[r] = p2[r * K4];
                }
                if (q + 3 < NQ) {
                    const float4* p = (q + 3 < bnd) ? (aP0 + (q + 3) * 64)
                                                    : (aP1 + (q + 3 - bnd) * 64);
                    a3 = *p;
                } else a3 = a1;
                #pragma unroll
                for (int r = 0; r < 10; ++r) {
                    acc[r] = fmaf(a1.x, wB[r].x, acc[r]);
                    acc[r] = fmaf(a1.y, wB[r].y, acc[r]);
                    acc[r] = fmaf(a1.z, wB[r].z, acc[r]);
                    acc[r] = fmaf(a1.w, wB[r].w, acc[r]);
                }
                a0 = a2; a1 = a3;
            }

            #pragma unroll
            for (int r = 0; r < 10; ++r) red[wv][r][lane] = acc[r];
            __syncthreads();

            if (wv < 2) {
                float gv[5];
                #pragma unroll
                for (int gate = 0; gate < 5; ++gate) {
                    int r = gate * 2 + wv;
                    gv[gate] = red[0][r][lane] + red[1][r][lane]
                             + red[2][r][lane] + red[3][r][lane] + bias[gate];
                }
                float f  = 1.f / (1.f + expf(-gv[0]));
                float i_ = 1.f / (1.f + expf(-gv[1]));
                float ch = tanhf(gv[2]);
                float o  = 1.f / (1.f + expf(-gv[3]));
                float e_ = 1.f / (1.f + expf(-gv[4]));

                c_reg = f * c_reg + i_ * ch;
                float hl = o * tanhf(c_reg);
                float hn = e_ * expf(hl) + (1.f - e_) * hl;

                const int hoff = (j >> 2) * 256 + lane * 4 + (j & 3);
                if (!isL1) {
                    h0buf[(t & 1) * (BB * HH) + hoff] = hn;
                } else {
                    h1buf[(tm1 & 1) * (BB * HH) + hoff] = hn;
                    lstm_out[((size_t)lane * SS + tm1) * HH + j] = hn;
                }
            }
        }
        xbar(bar, t);
    }
}

// ---------------- fallback per-step kernel (same geometry, global c) --------
__global__ __launch_bounds__(256, 2) void step512_kernel(
    const float* __restrict__ xT,
    const float* __restrict__ P0, const float* __restrict__ b0v,
    const float* __restrict__ P1, const float* __restrict__ b1v,
    float* __restrict__ h0buf, float* __restrict__ h1buf,
    float* __restrict__ c0buf, float* __restrict__ c1buf,
    float* __restrict__ lstm_out, int t)
{
    __shared__ float W_s[10 * 1024];
    __shared__ float red[4][10][64];

    const int tid  = threadIdx.x;
    const int lane = tid & 63;
    const int wv   = tid >> 6;
    const bool isL1 = (blockIdx.x >= 256);
    const int blk  = (int)blockIdx.x & 255;
    const int g    = (blk & 7) * 32 + (blk >> 3);
    const int j    = g * 2 + (wv & 1);

    const bool active = isL1 ? (t >= 1) : (t < SS);
    if (!active) return;

    const int K  = isL1 ? 1024 : 576;
    const int QK = K >> 2;
    const int NQ = QK >> 2;
    const int k0 = wv * QK;

    {
        const float* Pg = (isL1 ? P1 : P0) + (size_t)g * 10 * K;
        const int n4 = 10 * K / 4;
        for (int i = tid; i < n4; i += 256)
            *(float4*)&W_s[i * 4] = *(const float4*)(Pg + (size_t)i * 4);
    }
    __syncthreads();

    const int tm1 = t - 1;
    const float* h0prev = h0buf + ((t + 1) & 1) * (BB * HH);
    const float* h0cur  = h0buf + (tm1 & 1) * (BB * HH);
    const float* h1prev = h1buf + ((tm1 + 1) & 1) * (BB * HH);

    const float4* aP0;
    const float4* aP1;
    int bnd;
    if (!isL1) {
        if (wv == 0) {
            aP0 = (const float4*)(xT + (size_t)t * (INF * BB)) + lane;
            aP1 = (const float4*)h0prev + lane;
            bnd = 16;
        } else {
            aP0 = (const float4*)h0prev + (36 * wv - 16) * 64 + lane;
            aP1 = aP0;
            bnd = NQ;
        }
    } else {
        const float* src = (wv < 2) ? h0cur : h1prev;
        aP0 = (const float4*)src + (wv & 1) * 4096 + lane;
        aP1 = aP0;
        bnd = NQ;
    }

    const float4* wP = (const float4*)W_s + (k0 >> 2);
    const int K4 = K >> 2;

    float acc[10];
    #pragma unroll
    for (int r = 0; r < 10; ++r) acc[r] = 0.f;

    float4 wA[10], wB[10];
    float4 a0, a1, a2, a3;
    a0 = aP0[0];
    a1 = (1 < bnd) ? aP0[64] : aP1[(1 - bnd) * 64];
    #pragma unroll
    for (int r = 0; r < 10; ++r) wA[r] = wP[r * K4];

    for (int q = 0; q < NQ; q += 2) {
        {
            const float4* p1 = (const float4*)W_s + (k0 >> 2) + (q + 1);
            #pragma unroll
            for (int r = 0; r < 10; ++r) wB[r] = p1[r * K4];
        }
        if (q + 2 < NQ) {
            const float4* p = (q + 2 < bnd) ? (aP0 + (q + 2) * 64)
                                            : (aP1 + (q + 2 - bnd) * 64);
            a2 = *p;
        } else a2 = a0;
        #pragma unroll
        for (int r = 0; r < 10; ++r) {
            acc[r] = fmaf(a0.x, wA[r].x, acc[r]);
            acc[r] = fmaf(a0.y, wA[r].y, acc[r]);
            acc[r] = fmaf(a0.z, wA[r].z, acc[r]);
            acc[r] = fmaf(a0.w, wA[r].w, acc[r]);
        }
        if (q + 2 < NQ) {
            const float4* p2 = (const float4*)W_s + (k0 >> 2) + (q + 2);
            #pragma unroll
            for (int r = 0; r < 10; ++r) wA[r] = p2[r * K4];
        }
        if (q + 3 < NQ) {
            const float4* p = (q + 3 < bnd) ? (aP0 + (q + 3) * 64)
                                            : (aP1 + (q + 3 - bnd) * 64);
            a3 = *p;
        } else a3 = a1;
        #pragma unroll
        for (int r = 0; r < 10; ++r) {
            acc[r] = fmaf(a1.x, wB[r].x, acc[r]);
            acc[r] = fmaf(a1.y, wB[r].y, acc[r]);
            acc[r] = fmaf(a1.z, wB[r].z, acc[r]);
            acc[r] = fmaf(a1.w, wB[r].w, acc[r]);
        }
        a0 = a2; a1 = a3;
    }

    #pragma unroll
    for (int r = 0; r < 10; ++r) red[wv][r][lane] = acc[r];
    __syncthreads();

    if (wv < 2) {
        const float* bv = isL1 ? b1v : b0v;
        float gv[5];
        #pragma unroll
        for (int gate = 0; gate < 5; ++gate) {
            int r = gate * 2 + wv;
            gv[gate] = red[0][r][lane] + red[1][r][lane]
                     + red[2][r][lane] + red[3][r][lane] + bv[gate * HH + j];
        }
        float f  = 1.f / (1.f + expf(-gv[0]));
        float i_ = 1.f / (1.f + expf(-gv[1]));
        float ch = tanhf(gv[2]);
        float o  = 1.f / (1.f + expf(-gv[3]));
        float e_ = 1.f / (1.f + expf(-gv[4]));

        float* cb = (isL1 ? c1buf : c0buf) + j * BB + lane;
        float c = f * (*cb) + i_ * ch;
        *cb = c;
        float hl = o * tanhf(c);
        float hn = e_ * expf(hl) + (1.f - e_) * hl;

        const int hoff = (j >> 2) * 256 + lane * 4 + (j & 3);
        if (!isL1) {
            h0buf[(t & 1) * (BB * HH) + hoff] = hn;
        } else {
            h1buf[(tm1 & 1) * (BB * HH) + hoff] = hn;
            lstm_out[((size_t)lane * SS + tm1) * HH + j] = hn;
        }
    }
}

// ---------------- attention epilogue, one block per batch row ----------------
__global__ __launch_bounds__(256) void attn_kernel(
    const float* __restrict__ lstm_out,
    const float* __restrict__ Wa, const float* __restrict__ ba,
    const float* __restrict__ Wfc, const float* __restrict__ bfc,
    float* __restrict__ dout)
{
    const int b = blockIdx.x;
    const int tid = threadIdx.x;
    const int lane = tid & 63;
    const int wave = tid >> 6;

    __shared__ float wa_s[HH];
    __shared__ float logit[SS];
    __shared__ float wred[4];

    for (int ii = tid; ii < HH; ii += 256) wa_s[ii] = Wa[ii];
    __syncthreads();

    const float* Lb = lstm_out + (size_t)b * SS * HH;

    for (int tt = wave; tt < SS; tt += 4) {
        const float* rowp = Lb + (size_t)tt * HH;
        float s = 0.f;
        for (int jc = lane; jc < HH; jc += 64) s += rowp[jc] * wa_s[jc];
        #pragma unroll
        for (int off = 32; off > 0; off >>= 1) s += __shfl_down(s, off, 64);
        if (lane == 0) logit[tt] = s + ba[0];
    }
    __syncthreads();

    float m = -1e30f;
    for (int ii = tid; ii < SS; ii += 256) m = fmaxf(m, logit[ii]);
    #pragma unroll
    for (int off = 32; off > 0; off >>= 1) m = fmaxf(m, __shfl_down(m, off, 64));
    if (lane == 0) wred[wave] = m;
    __syncthreads();
    m = fmaxf(fmaxf(wred[0], wred[1]), fmaxf(wred[2], wred[3]));
    __syncthreads();

    float ssum = 0.f;
    for (int ii = tid; ii < SS; ii += 256) {
        float e = expf(logit[ii] - m);
        logit[ii] = e;
        ssum += e;
    }
    #pragma unroll
    for (int off = 32; off > 0; off >>= 1) ssum += __shfl_down(ssum, off, 64);
    if (lane == 0) wred[wave] = ssum;
    __syncthreads();
    ssum = wred[0] + wred[1] + wred[2] + wred[3];
    float inv = 1.f / ssum;
    __syncthreads();

    for (int ii = tid; ii < SS; ii += 256) {
        float a = logit[ii] * inv;
        logit[ii] = a;
        dout[BB + (size_t)b * SS + ii] = a;
    }
    __syncthreads();

    float ctx0 = 0.f, ctx1 = 0.f;
    for (int tt = 0; tt < SS; ++tt) {
        float a = logit[tt];
        ctx0 += a * Lb[(size_t)tt * HH + tid];
        ctx1 += a * Lb[(size_t)tt * HH + tid + 256];
    }

    float p = ctx0 * Wfc[tid] + ctx1 * Wfc[tid + 256];
    #pragma unroll
    for (int off = 32; off > 0; off >>= 1) p += __shfl_down(p, off, 64);
    __syncthreads();
    if (lane == 0) wred[wave] = p;
    __syncthreads();
    if (tid == 0) dout[b] = wred[0] + wred[1] + wred[2] + wred[3] + bfc[0];
}

extern "C" void kernel_launch(void* const* d_in, const int* in_sizes, int n_in,
                              void* d_out, int out_size, void* d_ws, size_t ws_size,
                              hipStream_t stream) {
    const float* x   = (const float*)d_in[0];
    const float* W0  = (const float*)d_in[1];
    const float* b0  = (const float*)d_in[2];
    const float* W1  = (const float*)d_in[3];
    const float* b1  = (const float*)d_in[4];
    const float* Wa  = (const float*)d_in[5];
    const float* ba  = (const float*)d_in[6];
    const float* Wfc = (const float*)d_in[7];
    const float* bfc = (const float*)d_in[8];
    float* out = (float*)d_out;
    float* ws  = (float*)d_ws;

    float* h0   = ws;                              // 2*H*B (quad-interleaved)
    float* h1   = h0 + 2 * BB * HH;                // 2*H*B
    float* c0   = h1 + 2 * BB * HH;                // H*B (fallback only)
    float* c1   = c0 + BB * HH;                    // H*B (fallback only)
    float* lstm = c1 + BB * HH;                    // B*S*H
    float* P0   = lstm + (size_t)BB * SS * HH;     // 2560*576
    float* P1   = P0 + (size_t)G5 * (INF + HH);    // 2560*1024
    float* xT   = P1 + (size_t)G5 * (HH + HH);     // S*IN*B
    // barrier words alias c0 (persist uses c_reg, not c0/c1; fallback uses c0/c1
    // and never touches bar — mutually exclusive paths)
    unsigned* bar = (unsigned*)c0;

    const int state_n = 6 * BB * HH;               // zeroes h0,h1,c0(bar),c1
    init_kernel<<<(state_n + 255) / 256, 256, 0, stream>>>(ws, state_n);

    repack_kernel<<<dim3((INF + HH) / 64, 40), 256, 0, stream>>>(W0, P0, INF + HH);
    repack_kernel<<<dim3((HH + HH) / 64, 40), 256, 0, stream>>>(W1, P1, HH + HH);
    xpose_kernel<<<SS, 256, 0, stream>>>(x, xT);

    void* args[] = { (void*)&xT, (void*)&P0, (void*)&b0, (void*)&P1, (void*)&b1,
                     (void*)&h0, (void*)&h1, (void*)&lstm, (void*)&bar };
    hipError_t cerr = hipLaunchCooperativeKernel((void*)persist_kernel,
                                                 dim3(512), dim3(256),
                                                 args, 0, stream);
    if (cerr != hipSuccess) {
        for (int t = 0; t <= SS; ++t) {
            step512_kernel<<<512, 256, 0, stream>>>(xT, P0, b0, P1, b1,
                                                    h0, h1, c0, c1, lstm, t);
        }
    }

    attn_kernel<<<BB, 256, 0, stream>>>(lstm, Wa, ba, Wfc, bfc, out);
}